// Round 5
// baseline (285.693 us; speedup 1.0000x reference)
//
#include <hip/hip_runtime.h>
#include <math.h>

#define CC 256      // channels
#define HW 65536    // 256*256 pixels
#define SS 256      // pooled spatial (16*16)

// ws float offsets. Border (bf16 split planes of Xn in MFMA frag order)
// overlays the Xt region, which is dead after calib_kernel (stream-ordered).
#define WS_XT    0        // Xt[s][c]   65536 floats (dead after calib)
#define WS_BORD  0        // Border: 196608 bf16 = 98304 float-slots (bprep output)
#define WS_XN    98304    // Xn[c][s]   65536 floats
#define WS_YG    163840   // pooled sup_y [256]
#define WS_INVN  164096   // 1/max(||Xn[:,n]||,1e-4) [256]
#define WS_SELF  164352   // sel flag [256]
// total 164608 floats = 658 KB

typedef __attribute__((ext_vector_type(8))) short short8;
typedef __attribute__((ext_vector_type(4))) float f32x4;

__device__ inline unsigned short bf16_rne(float f) {
    unsigned int u = __float_as_uint(f);
    return (unsigned short)((u + 0x7fffu + ((u >> 16) & 1u)) >> 16);
}
__device__ inline float bf16_f(unsigned short h) {
    return __uint_as_float(((unsigned int)h) << 16);
}

// ---------------------------------------------------------------- pooling
__global__ void pool_kernel(const float* __restrict__ sup_x,
                            const float* __restrict__ sup_y,
                            float* __restrict__ ws) {
    int blk = blockIdx.x;
    int t   = threadIdx.x;
    const float* src = (blk < CC) ? (sup_x + (size_t)blk * HW) : sup_y;

    for (int py = 0; py < 16; ++py) {
        float acc = 0.f;
        int hbase = py * 16;
        #pragma unroll
        for (int i = 0; i < 16; ++i)
            acc += src[(hbase + i) * 256 + t];
        acc += __shfl_down(acc, 8, 16);
        acc += __shfl_down(acc, 4, 16);
        acc += __shfl_down(acc, 2, 16);
        acc += __shfl_down(acc, 1, 16);
        if ((t & 15) == 0) {
            int cell = py * 16 + (t >> 4);
            float v = acc * (1.f / 256.f);
            if (blk < CC) ws[WS_XT + cell * SS + blk] = v;
            else          ws[WS_YG + cell] = v;
        }
    }
}

// ---------------------------------------------------- gram + softmax + Xn
__global__ void calib_kernel(const float* __restrict__ cal,
                             float* __restrict__ ws) {
    int i = blockIdx.x;
    int j = threadIdx.x;
    const float* Xt = ws + WS_XT;
    float* Xn = ws + WS_XN;

    __shared__ float xi[SS];
    __shared__ float red[256];
    __shared__ float e[CC];
    __shared__ float T[3];

    xi[j] = Xt[j * SS + i];
    __syncthreads();

    float d0 = 0.f, d1 = 0.f, d2 = 0.f, d3 = 0.f;
    #pragma unroll 4
    for (int s = 0; s < SS; s += 4) {
        d0 += xi[s + 0] * Xt[(s + 0) * SS + j];
        d1 += xi[s + 1] * Xt[(s + 1) * SS + j];
        d2 += xi[s + 2] * Xt[(s + 2) * SS + j];
        d3 += xi[s + 3] * Xt[(s + 3) * SS + j];
    }
    float dot = (d0 + d1) + (d2 + d3);

    red[j] = dot; __syncthreads();
    for (int off = 128; off > 0; off >>= 1) {
        if (j < off) red[j] = fmaxf(red[j], red[j + off]);
        __syncthreads();
    }
    float m = red[0];
    __syncthreads();

    float ev = expf(dot - m);
    e[j] = ev;
    red[j] = ev; __syncthreads();
    for (int off = 128; off > 0; off >>= 1) {
        if (j < off) red[j] += red[j + off];
        __syncthreads();
    }
    float esum = red[0];
    __syncthreads();

    if (j < 3) {
        int jj = i + j - 1;
        float tv = 0.f;
        if (jj >= 0 && jj < CC) {
            float soft = e[jj] / esum;
            tv = (1.f + 0.2f * soft) * cal[i * CC + jj];
        }
        T[j] = tv;
    }
    __syncthreads();

    float v = T[1] * xi[j];
    if (i > 0)      v += T[0] * Xt[j * SS + i - 1];
    if (i < CC - 1) v += T[2] * Xt[j * SS + i + 1];
    Xn[i * SS + j] = v;
}

// ------------------------------------------------ proto inv-norms + sel
__global__ void prep_kernel(float* __restrict__ ws) {
    int b = blockIdx.x;
    int t = threadIdx.x;
    int nn = t & 31, cg = t >> 5;
    int n = b * 32 + nn;
    const float* Xn = ws + WS_XN;
    float s = 0.f;
    #pragma unroll 8
    for (int c = cg * 32; c < cg * 32 + 32; ++c) {
        float v = Xn[c * SS + n];
        s += v * v;
    }
    __shared__ float red[256];
    red[t] = s;
    __syncthreads();
    if (t < 32) {
        float acc = 0.f;
        #pragma unroll
        for (int g = 0; g < 8; ++g) acc += red[g * 32 + t];
        ws[WS_INVN + n] = 1.f / fmaxf(sqrtf(acc), 1e-4f);
        ws[WS_SELF + n] = (ws[WS_YG + n] > 0.5f) ? 1.f : 0.f;
    }
}

// ---------------------------------------- B pre-split into MFMA frag order
// Border[c][s][t][L][j] (bf16) = split_s(Xn[k][n]),
//   k = c*32 + (L>>4)*8 + j,  n = t*16 + (L&15)
// so main-kernel chunk staging is a contiguous 48 KB copy and B-frag reads
// are lane-linear ds_read_b128.
__global__ void bprep_kernel(float* __restrict__ ws) {
    int rem = (blockIdx.x & 3) * 256 + threadIdx.x;  // 0..1023
    int c = blockIdx.x >> 2;                         // chunk 0..7
    int t = rem >> 6, L = rem & 63;
    int quad = L >> 4, nh = L & 15;
    int n = t * 16 + nh;
    int kb = c * 32 + quad * 8;
    const float* Xn = ws + WS_XN;

    union { unsigned short u[8]; uint4 v; } hh, mm, ll;
    #pragma unroll
    for (int j = 0; j < 8; ++j) {
        float f = Xn[(kb + j) * SS + n];
        unsigned short h = bf16_rne(f);
        float f1 = f - bf16_f(h);
        unsigned short m = bf16_rne(f1);
        float f2 = f1 - bf16_f(m);
        unsigned short l = bf16_rne(f2);
        hh.u[j] = h; mm.u[j] = m; ll.u[j] = l;
    }
    unsigned short* bord = (unsigned short*)(ws + WS_BORD);
    size_t base = ((((size_t)c * 3) * 16 + t) * 64 + L) * 8;  // s stride = 8192 shorts
    *reinterpret_cast<uint4*>(&bord[base])         = hh.v;
    *reinterpret_cast<uint4*>(&bord[base + 8192])  = mm.v;
    *reinterpret_cast<uint4*>(&bord[base + 16384]) = ll.v;
}

// ------------------------------------- fused MFMA GEMM + softmax + argmax
// Block: 64 px x 256 protos, 256 threads = 4 waves. Wave w: protos w*64..+63.
// Per wave: 4x4 tiles of 16x16, K=256 in 8 chunks of 32.
// 6 bf16 split-product passes (hh,hm,mh,mm,hl,lh) -> fp32-accurate dot.
// A gathered from global per-lane (frag order), split in-register; B staged
// in LDS from pre-swizzled Border.
#define NCH 8

__global__ __launch_bounds__(256)
void main_kernel(const float* __restrict__ qry,
                 const float* __restrict__ ws,
                 float* __restrict__ out) {
    __shared__ float4 bsm4[3072];   // 48 KB chunk buffer / epilogue scratch
    unsigned short* bsm = (unsigned short*)bsm4;
    float* smf = (float*)bsm4;

    int tid = threadIdx.x;
    int lane = tid & 63, w = tid >> 6;
    int quad = lane >> 4, nh = lane & 15;
    int p0 = blockIdx.x * 64;
    const unsigned short* bord = (const unsigned short*)(ws + WS_BORD);

    f32x4 acc[4][4];
    #pragma unroll
    for (int mt = 0; mt < 4; ++mt)
        #pragma unroll
        for (int nt = 0; nt < 4; ++nt)
            acc[mt][nt] = (f32x4){0.f, 0.f, 0.f, 0.f};

    float qsq[4] = {0.f, 0.f, 0.f, 0.f};

    #pragma unroll 1
    for (int c = 0; c < NCH; ++c) {
        __syncthreads();   // protect bsm from previous iteration's readers
        // stage B chunk: contiguous 48 KB copy (coalesced, L2-resident)
        {
            const float4* src = (const float4*)(bord + (size_t)c * 24576);
            #pragma unroll
            for (int i = 0; i < 12; ++i)
                bsm4[i * 256 + tid] = src[i * 256 + tid];
        }
        // gather A frags from global (per-lane, frag order) + 3-way split
        int k0 = c * 32 + quad * 8;
        short8 afr[4][3];
        #pragma unroll
        for (int mt = 0; mt < 4; ++mt) {
            float v[8];
            #pragma unroll
            for (int j = 0; j < 8; ++j)
                v[j] = qry[(size_t)(k0 + j) * HW + p0 + mt * 16 + nh];
            short8 ah, am, al;
            #pragma unroll
            for (int j = 0; j < 8; ++j) {
                qsq[mt] += v[j] * v[j];
                unsigned short h = bf16_rne(v[j]);
                float f1 = v[j] - bf16_f(h);
                unsigned short m = bf16_rne(f1);
                float f2 = f1 - bf16_f(m);
                unsigned short l = bf16_rne(f2);
                ah[j] = (short)h; am[j] = (short)m; al[j] = (short)l;
            }
            afr[mt][0] = ah; afr[mt][1] = am; afr[mt][2] = al;
        }
        __syncthreads();   // B staged

        #pragma unroll
        for (int h2 = 0; h2 < 2; ++h2) {
            #pragma unroll
            for (int ntl = 0; ntl < 2; ++ntl) {
                int nt = h2 * 2 + ntl;
                int tg = w * 4 + nt;
                short8 bh = *(const short8*)&bsm[(size_t)((0 * 16 + tg) * 64 + lane) * 8];
                short8 bm = *(const short8*)&bsm[(size_t)((1 * 16 + tg) * 64 + lane) * 8];
                short8 bl = *(const short8*)&bsm[(size_t)((2 * 16 + tg) * 64 + lane) * 8];
                #pragma unroll
                for (int mt = 0; mt < 4; ++mt) {
                    f32x4 a = acc[mt][nt];
                    a = __builtin_amdgcn_mfma_f32_16x16x32_bf16(afr[mt][2], bh, a, 0, 0, 0); // lh
                    a = __builtin_amdgcn_mfma_f32_16x16x32_bf16(afr[mt][0], bl, a, 0, 0, 0); // hl
                    a = __builtin_amdgcn_mfma_f32_16x16x32_bf16(afr[mt][1], bm, a, 0, 0, 0); // mm
                    a = __builtin_amdgcn_mfma_f32_16x16x32_bf16(afr[mt][1], bh, a, 0, 0, 0); // mh
                    a = __builtin_amdgcn_mfma_f32_16x16x32_bf16(afr[mt][0], bm, a, 0, 0, 0); // hm
                    a = __builtin_amdgcn_mfma_f32_16x16x32_bf16(afr[mt][0], bh, a, 0, 0, 0); // hh
                    acc[mt][nt] = a;
                }
            }
        }
    }
    __syncthreads();   // done with bsm as B buffer

    // ---- per-pixel ||q||^2 (combine quads via shfl), wave 0 publishes
    #pragma unroll
    for (int mt = 0; mt < 4; ++mt) {
        qsq[mt] += __shfl_xor(qsq[mt], 16);
        qsq[mt] += __shfl_xor(qsq[mt], 32);
    }
    float* pm    = smf;          // [64][65]
    float* pa    = smf + 4160;   // [64][65]
    float* invqs = smf + 8320;   // [64]
    float* mfin  = smf + 8384;   // [64]
    float* afin  = smf + 8448;   // [64]
    if (w == 0 && quad == 0) {
        #pragma unroll
        for (int mt = 0; mt < 4; ++mt)
            invqs[mt * 16 + nh] = 1.f / fmaxf(sqrtf(qsq[mt]), 1e-4f);
    }

    // per-lane proto scale factors
    float invn4[4], self4[4];
    #pragma unroll
    for (int nt = 0; nt < 4; ++nt) {
        int n = w * 64 + nt * 16 + nh;
        invn4[nt] = ws[WS_INVN + n];
        self4[nt] = ws[WS_SELF + n];
    }
    __syncthreads();   // invqs ready

    // ---- phase A: scale+mask, per-lane max/argmax over nt
    #pragma unroll
    for (int mt = 0; mt < 4; ++mt) {
        #pragma unroll
        for (int r = 0; r < 4; ++r) {
            int p = mt * 16 + quad * 4 + r;
            float iq = invqs[p] * 20.f;
            float bv = -3.4e38f, ba = 1e9f;
            #pragma unroll
            for (int nt = 0; nt < 4; ++nt) {
                float d = acc[mt][nt][r] * invn4[nt] * iq;
                d = (self4[nt] > 0.5f) ? d : -1e9f;
                acc[mt][nt][r] = d;
                float na = (float)(w * 64 + nt * 16 + nh);
                if (d > bv || (d == bv && na < ba)) { bv = d; ba = na; }
            }
            pm[p * 65 + w * 16 + nh] = bv;
            pa[p * 65 + w * 16 + nh] = ba;
        }
    }
    __syncthreads();

    // reduce 64 partials/pixel: 4 threads per pixel + shfl width 4
    {
        int p = tid >> 2, q4 = tid & 3;
        float bv = -3.4e38f, ba = 1e9f;
        #pragma unroll
        for (int jj = 0; jj < 16; ++jj) {
            int cx = q4 * 16 + jj;
            float v2 = pm[p * 65 + cx];
            float a2 = pa[p * 65 + cx];
            if (v2 > bv || (v2 == bv && a2 < ba)) { bv = v2; ba = a2; }
        }
        #pragma unroll
        for (int off = 1; off < 4; off <<= 1) {
            float ov = __shfl_xor(bv, off, 4);
            float oa = __shfl_xor(ba, off, 4);
            if (ov > bv || (ov == bv && oa < ba)) { bv = ov; ba = oa; }
        }
        if (q4 == 0) { mfin[p] = bv; afin[p] = ba; }
    }
    __syncthreads();

    // ---- phase B: exp-sums (reuse pm/pa as s1/s2 partials)
    #pragma unroll
    for (int mt = 0; mt < 4; ++mt) {
        #pragma unroll
        for (int r = 0; r < 4; ++r) {
            int p = mt * 16 + quad * 4 + r;
            float m = mfin[p];
            float s1 = 0.f, s2 = 0.f;
            #pragma unroll
            for (int nt = 0; nt < 4; ++nt) {
                float d = acc[mt][nt][r];
                float ev = expf(d - m);   // masked -1e9 -> 0
                s1 += ev;
                s2 += ev * d;
            }
            pm[p * 65 + w * 16 + nh] = s1;
            pa[p * 65 + w * 16 + nh] = s2;
        }
    }
    __syncthreads();

    {
        int p = tid >> 2, q4 = tid & 3;
        float s1 = 0.f, s2 = 0.f;
        #pragma unroll
        for (int jj = 0; jj < 16; ++jj) {
            int cx = q4 * 16 + jj;
            s1 += pm[p * 65 + cx];
            s2 += pa[p * 65 + cx];
        }
        #pragma unroll
        for (int off = 1; off < 4; off <<= 1) {
            s1 += __shfl_xor(s1, off, 4);
            s2 += __shfl_xor(s2, off, 4);
        }
        if (q4 == 0) {
            out[p0 + p]      = s2 / s1;    // pred_grid
            out[HW + p0 + p] = afin[p];    // debug_assign
        }
    }
}

// ----------------------------------------------------------------- launch
extern "C" void kernel_launch(void* const* d_in, const int* in_sizes, int n_in,
                              void* d_out, int out_size, void* d_ws, size_t ws_size,
                              hipStream_t stream) {
    const float* qry   = (const float*)d_in[0];
    const float* sup_x = (const float*)d_in[1];
    const float* sup_y = (const float*)d_in[2];
    // d_in[3] = s_init_seed (unused by reference)
    const float* cal   = (const float*)d_in[4];
    float* out = (float*)d_out;
    float* ws  = (float*)d_ws;

    pool_kernel<<<257, 256, 0, stream>>>(sup_x, sup_y, ws);
    calib_kernel<<<256, 256, 0, stream>>>(cal, ws);
    prep_kernel<<<8, 256, 0, stream>>>(ws);
    bprep_kernel<<<32, 256, 0, stream>>>(ws);
    main_kernel<<<HW / 64, 256, 0, stream>>>(qry, ws, out);
}

// Round 6
// 232.406 us; speedup vs baseline: 1.2293x; 1.2293x over previous
//
#include <hip/hip_runtime.h>
#include <math.h>

#define CC 256      // channels
#define HW 65536    // 256*256 pixels
#define SS 256      // pooled spatial (16*16)

// ws float offsets. Border (bf16 split planes of Xn in MFMA frag order)
// overlays the Xt region, which is dead after calib_kernel (stream-ordered).
#define WS_XT    0        // Xt[s][c]   65536 floats (dead after calib)
#define WS_BORD  0        // Border: 196608 bf16 = 98304 float-slots (bprep output)
#define WS_XN    98304    // Xn[c][s]   65536 floats
#define WS_YG    163840   // pooled sup_y [256]
#define WS_INVN  164096   // 1/max(||Xn[:,n]||,1e-4) [256]
#define WS_SELF  164352   // sel flag [256]
// total 164608 floats = 658 KB

typedef __attribute__((ext_vector_type(8))) short short8;
typedef __attribute__((ext_vector_type(4))) float f32x4;

__device__ inline unsigned short bf16_rne(float f) {
    unsigned int u = __float_as_uint(f);
    return (unsigned short)((u + 0x7fffu + ((u >> 16) & 1u)) >> 16);
}
__device__ inline float bf16_f(unsigned short h) {
    return __uint_as_float(((unsigned int)h) << 16);
}

// ---------------------------------------------------------------- pooling
__global__ void pool_kernel(const float* __restrict__ sup_x,
                            const float* __restrict__ sup_y,
                            float* __restrict__ ws) {
    int blk = blockIdx.x;
    int t   = threadIdx.x;
    const float* src = (blk < CC) ? (sup_x + (size_t)blk * HW) : sup_y;

    for (int py = 0; py < 16; ++py) {
        float acc = 0.f;
        int hbase = py * 16;
        #pragma unroll
        for (int i = 0; i < 16; ++i)
            acc += src[(hbase + i) * 256 + t];
        acc += __shfl_down(acc, 8, 16);
        acc += __shfl_down(acc, 4, 16);
        acc += __shfl_down(acc, 2, 16);
        acc += __shfl_down(acc, 1, 16);
        if ((t & 15) == 0) {
            int cell = py * 16 + (t >> 4);
            float v = acc * (1.f / 256.f);
            if (blk < CC) ws[WS_XT + cell * SS + blk] = v;
            else          ws[WS_YG + cell] = v;
        }
    }
}

// ---------------------------------------------------- gram + softmax + Xn
__global__ void calib_kernel(const float* __restrict__ cal,
                             float* __restrict__ ws) {
    int i = blockIdx.x;
    int j = threadIdx.x;
    const float* Xt = ws + WS_XT;
    float* Xn = ws + WS_XN;

    __shared__ float xi[SS];
    __shared__ float red[256];
    __shared__ float e[CC];
    __shared__ float T[3];

    xi[j] = Xt[j * SS + i];
    __syncthreads();

    float d0 = 0.f, d1 = 0.f, d2 = 0.f, d3 = 0.f;
    #pragma unroll 4
    for (int s = 0; s < SS; s += 4) {
        d0 += xi[s + 0] * Xt[(s + 0) * SS + j];
        d1 += xi[s + 1] * Xt[(s + 1) * SS + j];
        d2 += xi[s + 2] * Xt[(s + 2) * SS + j];
        d3 += xi[s + 3] * Xt[(s + 3) * SS + j];
    }
    float dot = (d0 + d1) + (d2 + d3);

    red[j] = dot; __syncthreads();
    for (int off = 128; off > 0; off >>= 1) {
        if (j < off) red[j] = fmaxf(red[j], red[j + off]);
        __syncthreads();
    }
    float m = red[0];
    __syncthreads();

    float ev = expf(dot - m);
    e[j] = ev;
    red[j] = ev; __syncthreads();
    for (int off = 128; off > 0; off >>= 1) {
        if (j < off) red[j] += red[j + off];
        __syncthreads();
    }
    float esum = red[0];
    __syncthreads();

    if (j < 3) {
        int jj = i + j - 1;
        float tv = 0.f;
        if (jj >= 0 && jj < CC) {
            float soft = e[jj] / esum;
            tv = (1.f + 0.2f * soft) * cal[i * CC + jj];
        }
        T[j] = tv;
    }
    __syncthreads();

    float v = T[1] * xi[j];
    if (i > 0)      v += T[0] * Xt[j * SS + i - 1];
    if (i < CC - 1) v += T[2] * Xt[j * SS + i + 1];
    Xn[i * SS + j] = v;
}

// ------------------------------------------------ proto inv-norms + sel
__global__ void prep_kernel(float* __restrict__ ws) {
    int b = blockIdx.x;
    int t = threadIdx.x;
    int nn = t & 31, cg = t >> 5;
    int n = b * 32 + nn;
    const float* Xn = ws + WS_XN;
    float s = 0.f;
    #pragma unroll 8
    for (int c = cg * 32; c < cg * 32 + 32; ++c) {
        float v = Xn[c * SS + n];
        s += v * v;
    }
    __shared__ float red[256];
    red[t] = s;
    __syncthreads();
    if (t < 32) {
        float acc = 0.f;
        #pragma unroll
        for (int g = 0; g < 8; ++g) acc += red[g * 32 + t];
        ws[WS_INVN + n] = 1.f / fmaxf(sqrtf(acc), 1e-4f);
        ws[WS_SELF + n] = (ws[WS_YG + n] > 0.5f) ? 1.f : 0.f;
    }
}

// ---------------------------------------- B pre-split into MFMA frag order
// Border[c][pl][t][L][j] (bf16) = split_pl(Xn[k][n]),
//   k = c*32 + (L>>4)*8 + j,  n = t*16 + (L&15)
// Lane-linear: main kernel lane reads one dwordx4 per (tile,plane) from L2.
__global__ void bprep_kernel(float* __restrict__ ws) {
    int rem = (blockIdx.x & 3) * 256 + threadIdx.x;  // 0..1023
    int c = blockIdx.x >> 2;                         // chunk 0..7
    int t = rem >> 6, L = rem & 63;
    int quad = L >> 4, nh = L & 15;
    int n = t * 16 + nh;
    int kb = c * 32 + quad * 8;
    const float* Xn = ws + WS_XN;

    union { unsigned short u[8]; uint4 v; } hh, mm, ll;
    #pragma unroll
    for (int j = 0; j < 8; ++j) {
        float f = Xn[(kb + j) * SS + n];
        unsigned short h = bf16_rne(f);
        float f1 = f - bf16_f(h);
        unsigned short m = bf16_rne(f1);
        float f2 = f1 - bf16_f(m);
        unsigned short l = bf16_rne(f2);
        hh.u[j] = h; mm.u[j] = m; ll.u[j] = l;
    }
    unsigned short* bord = (unsigned short*)(ws + WS_BORD);
    size_t base = ((((size_t)c * 3) * 16 + t) * 64 + L) * 8;  // plane stride = 8192 shorts
    *reinterpret_cast<uint4*>(&bord[base])         = hh.v;
    *reinterpret_cast<uint4*>(&bord[base + 8192])  = mm.v;
    *reinterpret_cast<uint4*>(&bord[base + 16384]) = ll.v;
}

// ------------------------------------- fused MFMA GEMM + softmax + argmax
// Block: 64 px x 256 protos, 4 waves, wave w -> protos w*64..+63.
// BARRIER-FREE K-loop: B frags read directly from L2-resident Border
// (384 KB, shared by all blocks); A gathered from qry + split in-register.
// 6 bf16 split-product passes -> fp32-accurate. LDS only for the epilogue.
#define NCH 8

__global__ __launch_bounds__(256)
void main_kernel(const float* __restrict__ qry,
                 const float* __restrict__ ws,
                 float* __restrict__ out) {
    __shared__ float pm[64 * 65];    // partial max / s1
    __shared__ float pa[64 * 65];    // partial arg / s2
    __shared__ float invqs[64];
    __shared__ float mfin[64];
    __shared__ float afin[64];

    int tid = threadIdx.x;
    int lane = tid & 63, w = tid >> 6;
    int quad = lane >> 4, nh = lane & 15;
    int p0 = blockIdx.x * 64;
    const unsigned short* bord = (const unsigned short*)(ws + WS_BORD);

    f32x4 acc[4][4];
    #pragma unroll
    for (int mt = 0; mt < 4; ++mt)
        #pragma unroll
        for (int nt = 0; nt < 4; ++nt)
            acc[mt][nt] = (f32x4){0.f, 0.f, 0.f, 0.f};

    float qsq[4] = {0.f, 0.f, 0.f, 0.f};

    #pragma unroll 1
    for (int c = 0; c < NCH; ++c) {
        // gather A frags from global (per-lane, frag order) + 3-way split
        int k0 = c * 32 + quad * 8;
        short8 afr[4][3];
        #pragma unroll
        for (int mt = 0; mt < 4; ++mt) {
            float v[8];
            #pragma unroll
            for (int j = 0; j < 8; ++j)
                v[j] = qry[(size_t)(k0 + j) * HW + p0 + mt * 16 + nh];
            short8 ah, am, al;
            #pragma unroll
            for (int j = 0; j < 8; ++j) {
                qsq[mt] += v[j] * v[j];
                unsigned short h = bf16_rne(v[j]);
                float f1 = v[j] - bf16_f(h);
                unsigned short m = bf16_rne(f1);
                float f2 = f1 - bf16_f(m);
                unsigned short l = bf16_rne(f2);
                ah[j] = (short)h; am[j] = (short)m; al[j] = (short)l;
            }
            afr[mt][0] = ah; afr[mt][1] = am; afr[mt][2] = al;
        }

        const unsigned short* bc = bord + (size_t)c * 24576;
        #pragma unroll
        for (int nt = 0; nt < 4; ++nt) {
            int tg = w * 4 + nt;
            short8 bh = *(const short8*)&bc[(size_t)((0 * 16 + tg) * 64 + lane) * 8];
            short8 bm = *(const short8*)&bc[(size_t)((1 * 16 + tg) * 64 + lane) * 8];
            short8 bl = *(const short8*)&bc[(size_t)((2 * 16 + tg) * 64 + lane) * 8];
            #pragma unroll
            for (int mt = 0; mt < 4; ++mt) {
                f32x4 a = acc[mt][nt];
                a = __builtin_amdgcn_mfma_f32_16x16x32_bf16(afr[mt][2], bh, a, 0, 0, 0); // lh
                a = __builtin_amdgcn_mfma_f32_16x16x32_bf16(afr[mt][0], bl, a, 0, 0, 0); // hl
                a = __builtin_amdgcn_mfma_f32_16x16x32_bf16(afr[mt][1], bm, a, 0, 0, 0); // mm
                a = __builtin_amdgcn_mfma_f32_16x16x32_bf16(afr[mt][1], bh, a, 0, 0, 0); // mh
                a = __builtin_amdgcn_mfma_f32_16x16x32_bf16(afr[mt][0], bm, a, 0, 0, 0); // hm
                a = __builtin_amdgcn_mfma_f32_16x16x32_bf16(afr[mt][0], bh, a, 0, 0, 0); // hh
                acc[mt][nt] = a;
            }
        }
    }

    // ---- per-pixel ||q||^2 (combine quads via shfl), wave 0 publishes
    #pragma unroll
    for (int mt = 0; mt < 4; ++mt) {
        qsq[mt] += __shfl_xor(qsq[mt], 16);
        qsq[mt] += __shfl_xor(qsq[mt], 32);
    }
    if (w == 0 && quad == 0) {
        #pragma unroll
        for (int mt = 0; mt < 4; ++mt)
            invqs[mt * 16 + nh] = 1.f / fmaxf(sqrtf(qsq[mt]), 1e-4f);
    }

    // per-lane proto scale factors
    float invn4[4], self4[4];
    #pragma unroll
    for (int nt = 0; nt < 4; ++nt) {
        int n = w * 64 + nt * 16 + nh;
        invn4[nt] = ws[WS_INVN + n];
        self4[nt] = ws[WS_SELF + n];
    }
    __syncthreads();   // invqs ready

    // ---- phase A: scale+mask, per-lane max/argmax over nt
    #pragma unroll
    for (int mt = 0; mt < 4; ++mt) {
        #pragma unroll
        for (int r = 0; r < 4; ++r) {
            int p = mt * 16 + quad * 4 + r;
            float iq = invqs[p] * 20.f;
            float bv = -3.4e38f, ba = 1e9f;
            #pragma unroll
            for (int nt = 0; nt < 4; ++nt) {
                float d = acc[mt][nt][r] * invn4[nt] * iq;
                d = (self4[nt] > 0.5f) ? d : -1e9f;
                acc[mt][nt][r] = d;
                float na = (float)(w * 64 + nt * 16 + nh);
                if (d > bv || (d == bv && na < ba)) { bv = d; ba = na; }
            }
            pm[p * 65 + w * 16 + nh] = bv;
            pa[p * 65 + w * 16 + nh] = ba;
        }
    }
    __syncthreads();

    // reduce 64 partials/pixel: 4 threads per pixel + shfl width 4
    {
        int p = tid >> 2, q4 = tid & 3;
        float bv = -3.4e38f, ba = 1e9f;
        #pragma unroll
        for (int jj = 0; jj < 16; ++jj) {
            int cx = q4 * 16 + jj;
            float v2 = pm[p * 65 + cx];
            float a2 = pa[p * 65 + cx];
            if (v2 > bv || (v2 == bv && a2 < ba)) { bv = v2; ba = a2; }
        }
        #pragma unroll
        for (int off = 1; off < 4; off <<= 1) {
            float ov = __shfl_xor(bv, off, 4);
            float oa = __shfl_xor(ba, off, 4);
            if (ov > bv || (ov == bv && oa < ba)) { bv = ov; ba = oa; }
        }
        if (q4 == 0) { mfin[p] = bv; afin[p] = ba; }
    }
    __syncthreads();

    // ---- phase B: exp-sums (reuse pm/pa as s1/s2 partials)
    #pragma unroll
    for (int mt = 0; mt < 4; ++mt) {
        #pragma unroll
        for (int r = 0; r < 4; ++r) {
            int p = mt * 16 + quad * 4 + r;
            float m = mfin[p];
            float s1 = 0.f, s2 = 0.f;
            #pragma unroll
            for (int nt = 0; nt < 4; ++nt) {
                float d = acc[mt][nt][r];
                float ev = expf(d - m);   // masked -1e9 -> 0
                s1 += ev;
                s2 += ev * d;
            }
            pm[p * 65 + w * 16 + nh] = s1;
            pa[p * 65 + w * 16 + nh] = s2;
        }
    }
    __syncthreads();

    {
        int p = tid >> 2, q4 = tid & 3;
        float s1 = 0.f, s2 = 0.f;
        #pragma unroll
        for (int jj = 0; jj < 16; ++jj) {
            int cx = q4 * 16 + jj;
            s1 += pm[p * 65 + cx];
            s2 += pa[p * 65 + cx];
        }
        #pragma unroll
        for (int off = 1; off < 4; off <<= 1) {
            s1 += __shfl_xor(s1, off, 4);
            s2 += __shfl_xor(s2, off, 4);
        }
        if (q4 == 0) {
            out[p0 + p]      = s2 / s1;    // pred_grid
            out[HW + p0 + p] = afin[p];    // debug_assign
        }
    }
}

// ----------------------------------------------------------------- launch
extern "C" void kernel_launch(void* const* d_in, const int* in_sizes, int n_in,
                              void* d_out, int out_size, void* d_ws, size_t ws_size,
                              hipStream_t stream) {
    const float* qry   = (const float*)d_in[0];
    const float* sup_x = (const float*)d_in[1];
    const float* sup_y = (const float*)d_in[2];
    // d_in[3] = s_init_seed (unused by reference)
    const float* cal   = (const float*)d_in[4];
    float* out = (float*)d_out;
    float* ws  = (float*)d_ws;

    pool_kernel<<<257, 256, 0, stream>>>(sup_x, sup_y, ws);
    calib_kernel<<<256, 256, 0, stream>>>(cal, ws);
    prep_kernel<<<8, 256, 0, stream>>>(ws);
    bprep_kernel<<<32, 256, 0, stream>>>(ws);
    main_kernel<<<HW / 64, 256, 0, stream>>>(qry, ws, out);
}

// Round 7
// 215.360 us; speedup vs baseline: 1.3266x; 1.0792x over previous
//
#include <hip/hip_runtime.h>
#include <math.h>

#define CC 256      // channels
#define HW 65536    // 256*256 pixels
#define SS 256      // pooled spatial (16*16)

// ws float offsets. Border (bf16 split planes of Xn in MFMA frag order)
// overlays the Xt region, which is dead after calib_kernel (stream-ordered).
#define WS_XT    0        // Xt[s][c]   65536 floats (dead after calib)
#define WS_BORD  0        // Border: 196608 bf16 = 98304 float-slots
#define WS_XN    98304    // Xn[c][s]   65536 floats
#define WS_YG    163840   // pooled sup_y [256]
#define WS_INVN  164096   // 1/max(||Xn[:,n]||,1e-4) [256]
#define WS_SELF  164352   // sel flag [256]
// total 164608 floats = 658 KB

typedef __attribute__((ext_vector_type(8))) short short8;
typedef __attribute__((ext_vector_type(4))) float f32x4;

__device__ inline unsigned short bf16_rne(float f) {
    unsigned int u = __float_as_uint(f);
    return (unsigned short)((u + 0x7fffu + ((u >> 16) & 1u)) >> 16);
}
__device__ inline float bf16_f(unsigned short h) {
    return __uint_as_float(((unsigned int)h) << 16);
}

// ---------------------------------------------------------------- pooling
// blocks 0..511: (channel = blk>>1, py-half = blk&1) of sup_x
// block 512:     sup_y (all 16 rows)
__global__ void pool_kernel(const float* __restrict__ sup_x,
                            const float* __restrict__ sup_y,
                            float* __restrict__ ws) {
    int blk = blockIdx.x;
    int t   = threadIdx.x;
    int ch   = (blk < 512) ? (blk >> 1) : CC;
    int pyb  = (blk < 512) ? ((blk & 1) * 8) : 0;
    int pye  = (blk < 512) ? (pyb + 8) : 16;
    const float* src = (blk < 512) ? (sup_x + (size_t)ch * HW) : sup_y;

    for (int py = pyb; py < pye; ++py) {
        float acc = 0.f;
        int hbase = py * 16;
        #pragma unroll
        for (int i = 0; i < 16; ++i)
            acc += src[(hbase + i) * 256 + t];
        acc += __shfl_down(acc, 8, 16);
        acc += __shfl_down(acc, 4, 16);
        acc += __shfl_down(acc, 2, 16);
        acc += __shfl_down(acc, 1, 16);
        if ((t & 15) == 0) {
            int cell = py * 16 + (t >> 4);
            float v = acc * (1.f / 256.f);
            if (blk < 512) ws[WS_XT + cell * SS + ch] = v;
            else           ws[WS_YG + cell] = v;
        }
    }
}

// ---------------------------------------------------- gram + softmax + Xn
__global__ void calib_kernel(const float* __restrict__ cal,
                             float* __restrict__ ws) {
    int i = blockIdx.x;
    int j = threadIdx.x;
    const float* Xt = ws + WS_XT;
    float* Xn = ws + WS_XN;

    __shared__ float xi[SS];
    __shared__ float red[256];
    __shared__ float e[CC];
    __shared__ float T[3];

    xi[j] = Xt[j * SS + i];
    __syncthreads();

    float d0 = 0.f, d1 = 0.f, d2 = 0.f, d3 = 0.f;
    #pragma unroll 4
    for (int s = 0; s < SS; s += 4) {
        d0 += xi[s + 0] * Xt[(s + 0) * SS + j];
        d1 += xi[s + 1] * Xt[(s + 1) * SS + j];
        d2 += xi[s + 2] * Xt[(s + 2) * SS + j];
        d3 += xi[s + 3] * Xt[(s + 3) * SS + j];
    }
    float dot = (d0 + d1) + (d2 + d3);

    red[j] = dot; __syncthreads();
    for (int off = 128; off > 0; off >>= 1) {
        if (j < off) red[j] = fmaxf(red[j], red[j + off]);
        __syncthreads();
    }
    float m = red[0];
    __syncthreads();

    float ev = expf(dot - m);
    e[j] = ev;
    red[j] = ev; __syncthreads();
    for (int off = 128; off > 0; off >>= 1) {
        if (j < off) red[j] += red[j + off];
        __syncthreads();
    }
    float esum = red[0];
    __syncthreads();

    if (j < 3) {
        int jj = i + j - 1;
        float tv = 0.f;
        if (jj >= 0 && jj < CC) {
            float soft = e[jj] / esum;
            tv = (1.f + 0.2f * soft) * cal[i * CC + jj];
        }
        T[j] = tv;
    }
    __syncthreads();

    float v = T[1] * xi[j];
    if (i > 0)      v += T[0] * Xt[j * SS + i - 1];
    if (i < CC - 1) v += T[2] * Xt[j * SS + i + 1];
    Xn[i * SS + j] = v;
}

// ---------------------- fused proto-norms/sel (blocks 0..7) + B pre-split
// (blocks 8..39). Both read Xn only; disjoint writes.
__global__ void prep_bprep_kernel(float* __restrict__ ws) {
    const float* Xn = ws + WS_XN;
    if (blockIdx.x < 8) {
        int b = blockIdx.x;
        int t = threadIdx.x;
        int nn = t & 31, cg = t >> 5;
        int n = b * 32 + nn;
        float s = 0.f;
        #pragma unroll 8
        for (int c = cg * 32; c < cg * 32 + 32; ++c) {
            float v = Xn[c * SS + n];
            s += v * v;
        }
        __shared__ float red[256];
        red[t] = s;
        __syncthreads();
        if (t < 32) {
            float acc = 0.f;
            #pragma unroll
            for (int g = 0; g < 8; ++g) acc += red[g * 32 + t];
            ws[WS_INVN + n] = 1.f / fmaxf(sqrtf(acc), 1e-4f);
            ws[WS_SELF + n] = (ws[WS_YG + n] > 0.5f) ? 1.f : 0.f;
        }
    } else {
        int blk = blockIdx.x - 8;                        // 0..31
        int rem = (blk & 3) * 256 + threadIdx.x;         // 0..1023
        int c = blk >> 2;                                // chunk 0..7
        int t = rem >> 6, L = rem & 63;
        int quad = L >> 4, nh = L & 15;
        int n = t * 16 + nh;
        int kb = c * 32 + quad * 8;

        union { unsigned short u[8]; uint4 v; } hh, mm, ll;
        #pragma unroll
        for (int j = 0; j < 8; ++j) {
            float f = Xn[(kb + j) * SS + n];
            unsigned short h = bf16_rne(f);
            float f1 = f - bf16_f(h);
            unsigned short m = bf16_rne(f1);
            float f2 = f1 - bf16_f(m);
            unsigned short l = bf16_rne(f2);
            hh.u[j] = h; mm.u[j] = m; ll.u[j] = l;
        }
        unsigned short* bord = (unsigned short*)(ws + WS_BORD);
        size_t base = ((((size_t)c * 3) * 16 + t) * 64 + L) * 8;
        *reinterpret_cast<uint4*>(&bord[base])         = hh.v;
        *reinterpret_cast<uint4*>(&bord[base + 8192])  = mm.v;
        *reinterpret_cast<uint4*>(&bord[base + 16384]) = ll.v;
    }
}

// ------------------------------------- fused MFMA GEMM + softmax + argmax
// Barrier-free K-loop, software-pipelined A:
//   split(va) -> afr ; prefetch va(c+1) ; B-loads + 96 MFMA (uses afr)
// Trunc-split (exact residuals): h=top16(f), m=top16(f-h), l=top16(f-h-m);
// 6 products (hh,hm,mh,mm,hl,lh) -> ~3*2^-24 relative error (fp32-class).
#define NCH 8

__global__ __launch_bounds__(256)
void main_kernel(const float* __restrict__ qry,
                 const float* __restrict__ ws,
                 float* __restrict__ out) {
    __shared__ float pm[64 * 65];    // partial max / s1
    __shared__ float pa[64 * 65];    // partial arg / s2
    __shared__ float invqs[64];
    __shared__ float mfin[64];
    __shared__ float afin[64];

    int tid = threadIdx.x;
    int lane = tid & 63, w = tid >> 6;
    int quad = lane >> 4, nh = lane & 15;
    int p0 = blockIdx.x * 64;
    const unsigned short* bord = (const unsigned short*)(ws + WS_BORD);
    const float* qb = qry + p0 + nh;    // + k*HW + mt*16

    f32x4 acc[4][4];
    #pragma unroll
    for (int mt = 0; mt < 4; ++mt)
        #pragma unroll
        for (int nt = 0; nt < 4; ++nt)
            acc[mt][nt] = (f32x4){0.f, 0.f, 0.f, 0.f};

    float qsq[4] = {0.f, 0.f, 0.f, 0.f};

    // prologue: load chunk 0's A
    float va[4][8];
    #pragma unroll
    for (int mt = 0; mt < 4; ++mt)
        #pragma unroll
        for (int j = 0; j < 8; ++j)
            va[mt][j] = qb[(size_t)(quad * 8 + j) * HW + mt * 16];

    #pragma unroll 1
    for (int c = 0; c < NCH; ++c) {
        // split resident va -> afr (exact trunc residuals), accumulate qsq
        short8 afr[4][3];
        #pragma unroll
        for (int mt = 0; mt < 4; ++mt) {
            short8 ah, am, al;
            #pragma unroll
            for (int j = 0; j < 8; ++j) {
                float f = va[mt][j];
                qsq[mt] += f * f;
                unsigned int u = __float_as_uint(f);
                ah[j] = (short)(u >> 16);
                float f1 = f - __uint_as_float(u & 0xffff0000u);
                unsigned int u1 = __float_as_uint(f1);
                am[j] = (short)(u1 >> 16);
                float f2 = f1 - __uint_as_float(u1 & 0xffff0000u);
                al[j] = (short)(__float_as_uint(f2) >> 16);
            }
            afr[mt][0] = ah; afr[mt][1] = am; afr[mt][2] = al;
        }

        // prefetch next chunk's A (in flight under B-loads + MFMA)
        if (c + 1 < NCH) {
            int k0n = (c + 1) * 32 + quad * 8;
            #pragma unroll
            for (int mt = 0; mt < 4; ++mt)
                #pragma unroll
                for (int j = 0; j < 8; ++j)
                    va[mt][j] = qb[(size_t)(k0n + j) * HW + mt * 16];
        }

        const unsigned short* bc = bord + (size_t)c * 24576;
        #pragma unroll
        for (int nt = 0; nt < 4; ++nt) {
            int tg = w * 4 + nt;
            short8 bh = *(const short8*)&bc[(size_t)((0 * 16 + tg) * 64 + lane) * 8];
            short8 bm = *(const short8*)&bc[(size_t)((1 * 16 + tg) * 64 + lane) * 8];
            short8 bl = *(const short8*)&bc[(size_t)((2 * 16 + tg) * 64 + lane) * 8];
            #pragma unroll
            for (int mt = 0; mt < 4; ++mt) {
                f32x4 a = acc[mt][nt];
                a = __builtin_amdgcn_mfma_f32_16x16x32_bf16(afr[mt][2], bh, a, 0, 0, 0); // lh
                a = __builtin_amdgcn_mfma_f32_16x16x32_bf16(afr[mt][0], bl, a, 0, 0, 0); // hl
                a = __builtin_amdgcn_mfma_f32_16x16x32_bf16(afr[mt][1], bm, a, 0, 0, 0); // mm
                a = __builtin_amdgcn_mfma_f32_16x16x32_bf16(afr[mt][1], bh, a, 0, 0, 0); // mh
                a = __builtin_amdgcn_mfma_f32_16x16x32_bf16(afr[mt][0], bm, a, 0, 0, 0); // hm
                a = __builtin_amdgcn_mfma_f32_16x16x32_bf16(afr[mt][0], bh, a, 0, 0, 0); // hh
                acc[mt][nt] = a;
            }
        }
    }

    // ---- per-pixel ||q||^2 (sum quads via shfl; identical across waves)
    #pragma unroll
    for (int mt = 0; mt < 4; ++mt) {
        qsq[mt] += __shfl_xor(qsq[mt], 16);
        qsq[mt] += __shfl_xor(qsq[mt], 32);
    }
    if (w == 0 && quad == 0) {
        #pragma unroll
        for (int mt = 0; mt < 4; ++mt)
            invqs[mt * 16 + nh] = 1.f / fmaxf(sqrtf(qsq[mt]), 1e-4f);
    }

    // per-lane proto scale factors
    float invn4[4], self4[4];
    #pragma unroll
    for (int nt = 0; nt < 4; ++nt) {
        int n = w * 64 + nt * 16 + nh;
        invn4[nt] = ws[WS_INVN + n];
        self4[nt] = ws[WS_SELF + n];
    }
    __syncthreads();   // invqs ready

    // ---- phase A: scale+mask, per-lane max/argmax over nt
    #pragma unroll
    for (int mt = 0; mt < 4; ++mt) {
        #pragma unroll
        for (int r = 0; r < 4; ++r) {
            int p = mt * 16 + quad * 4 + r;
            float iq = invqs[p] * 20.f;
            float bv = -3.4e38f, ba = 1e9f;
            #pragma unroll
            for (int nt = 0; nt < 4; ++nt) {
                float d = acc[mt][nt][r] * invn4[nt] * iq;
                d = (self4[nt] > 0.5f) ? d : -1e9f;
                acc[mt][nt][r] = d;
                float na = (float)(w * 64 + nt * 16 + nh);
                if (d > bv || (d == bv && na < ba)) { bv = d; ba = na; }
            }
            pm[p * 65 + w * 16 + nh] = bv;
            pa[p * 65 + w * 16 + nh] = ba;
        }
    }
    __syncthreads();

    // reduce 64 partials/pixel: 4 threads per pixel + shfl width 4
    {
        int p = tid >> 2, q4 = tid & 3;
        float bv = -3.4e38f, ba = 1e9f;
        #pragma unroll
        for (int jj = 0; jj < 16; ++jj) {
            int cx = q4 * 16 + jj;
            float v2 = pm[p * 65 + cx];
            float a2 = pa[p * 65 + cx];
            if (v2 > bv || (v2 == bv && a2 < ba)) { bv = v2; ba = a2; }
        }
        #pragma unroll
        for (int off = 1; off < 4; off <<= 1) {
            float ov = __shfl_xor(bv, off, 4);
            float oa = __shfl_xor(ba, off, 4);
            if (ov > bv || (ov == bv && oa < ba)) { bv = ov; ba = oa; }
        }
        if (q4 == 0) { mfin[p] = bv; afin[p] = ba; }
    }
    __syncthreads();

    // ---- phase B: exp-sums (reuse pm/pa as s1/s2 partials)
    #pragma unroll
    for (int mt = 0; mt < 4; ++mt) {
        #pragma unroll
        for (int r = 0; r < 4; ++r) {
            int p = mt * 16 + quad * 4 + r;
            float m = mfin[p];
            float s1 = 0.f, s2 = 0.f;
            #pragma unroll
            for (int nt = 0; nt < 4; ++nt) {
                float d = acc[mt][nt][r];
                float ev = expf(d - m);   // masked -1e9 -> 0
                s1 += ev;
                s2 += ev * d;
            }
            pm[p * 65 + w * 16 + nh] = s1;
            pa[p * 65 + w * 16 + nh] = s2;
        }
    }
    __syncthreads();

    {
        int p = tid >> 2, q4 = tid & 3;
        float s1 = 0.f, s2 = 0.f;
        #pragma unroll
        for (int jj = 0; jj < 16; ++jj) {
            int cx = q4 * 16 + jj;
            s1 += pm[p * 65 + cx];
            s2 += pa[p * 65 + cx];
        }
        #pragma unroll
        for (int off = 1; off < 4; off <<= 1) {
            s1 += __shfl_xor(s1, off, 4);
            s2 += __shfl_xor(s2, off, 4);
        }
        if (q4 == 0) {
            out[p0 + p]      = s2 / s1;    // pred_grid
            out[HW + p0 + p] = afin[p];    // debug_assign
        }
    }
}

// ----------------------------------------------------------------- launch
extern "C" void kernel_launch(void* const* d_in, const int* in_sizes, int n_in,
                              void* d_out, int out_size, void* d_ws, size_t ws_size,
                              hipStream_t stream) {
    const float* qry   = (const float*)d_in[0];
    const float* sup_x = (const float*)d_in[1];
    const float* sup_y = (const float*)d_in[2];
    // d_in[3] = s_init_seed (unused by reference)
    const float* cal   = (const float*)d_in[4];
    float* out = (float*)d_out;
    float* ws  = (float*)d_ws;

    pool_kernel<<<513, 256, 0, stream>>>(sup_x, sup_y, ws);
    calib_kernel<<<256, 256, 0, stream>>>(cal, ws);
    prep_bprep_kernel<<<40, 256, 0, stream>>>(ws);
    main_kernel<<<HW / 64, 256, 0, stream>>>(qry, ws, out);
}